// Round 1
// 343.822 us; speedup vs baseline: 1.0186x; 1.0186x over previous
//
#include <hip/hip_runtime.h>
#include <cstdint>

#define D_CH 128
#define T_LEN 1024
#define ROWLEN 384
#define NROWS (128 * 1024)
#define TILE 64
#define NCHUNK (NROWS / TILE)   // 2048
#define VSTR_B 272              // vs row stride bytes (136 f16) — conflict-free b128 reads
#define EPI_W 132               // epi row stride words (pad 4) — 2-way max banks on scatter
#define SLICE_B 8448            // per-wave UNIFIED slice = max(16*VSTR_B=4352, 16*EPI_W*4=8448)

typedef __attribute__((ext_vector_type(8))) _Float16 f16x8;
typedef __attribute__((ext_vector_type(4))) _Float16 f16x4;
typedef __attribute__((ext_vector_type(4))) float f32x4;

// Kernel A: per-(b,d) mean over T + kernel matrix -> f16 in MFMA-B fragment order.
// Now 1024 threads/block (16 waves/CU vs 4): 4x memory-level parallelism for the
// latency-bound strided mean pass. Loads stay NORMAL (not nt) so y warms L3 for main.
__global__ __launch_bounds__(1024) void prep_kernel(const float* __restrict__ x,
                                                    const float* __restrict__ Kmat,
                                                    float* __restrict__ meang,
                                                    _Float16* __restrict__ Ktg) {
  int bid = blockIdx.x;            // 256 blocks: (b, half-of-D)
  int b = bid >> 1, h = bid & 1;
  int tid = threadIdx.x;
  int li = tid & 15, tt = tid >> 4;      // 16 d-groups x 64 t-slices
  int d4 = h * 64 + 4 * li;
  f32x4 s = {0.f, 0.f, 0.f, 0.f};
  const float* xp = x + (size_t)b * T_LEN * ROWLEN + d4;
#pragma unroll 4
  for (int j = 0; j < 16; ++j) {
    int t = tt + 64 * j;
    f32x4 v = *(const f32x4*)(xp + (size_t)t * ROWLEN);
    s += v;
  }
  __shared__ f32x4 red[64][17];          // 17408 B
  red[tt][li] = s;
  __syncthreads();
  for (int st = 32; st > 0; st >>= 1) {
    if (tt < st) red[tt][li] += red[tt + st][li];
    __syncthreads();
  }
  if (tt == 0) {
    f32x4 m = red[0][li] * (1.0f / 1024.0f);
    *(f32x4*)(meang + b * D_CH + d4) = m;
  }
  // fragment-order Kt: 64 f16 per block (16384 total, bijective)
  if (tid < 64) {
    int f = bid * 64 + tid;
    int j = f & 7;
    int lane = (f >> 3) & 63;
    int q = f >> 9;                 // 0..31 = nt*4 + ks
    int ks = q & 3, nt = q >> 2;
    int kk = ks * 32 + (lane >> 4) * 8 + j;
    int nn = nt * 16 + (lane & 15);
    Ktg[f] = (_Float16)Kmat[kk * D_CH + nn];
  }
}

// Kernel B: fused softmax + MFMA matmul + vectorized epilogue. ZERO barriers.
// Changes vs prev round:
//  - vsbuf/epibuf ALIASED into one per-wave slice (vslice dead once A-frags are in regs;
//    every epi ds_write data-depends on those ds_reads via the MFMA accumulator, and the
//    per-wave DS pipe is in-order, so write-after-read is safe). LDS 51200 -> 33792 B,
//    occupancy 3 -> 4 blocks/CU (12 -> 16 waves); 2048 blocks = exactly 2 full rounds.
//  - __launch_bounds__(256,4) to cap VGPRs <= 128 for the 4-block residency.
//  - nontemporal stores for all out streams + nontemporal loads for last-use x reads:
//    out (192 MiB) no longer thrashes L3, so the y-third warmed by prep stays resident
//    and main's y read becomes an Infinity-Cache hit (~67 MB less HBM fetch).
__global__ __launch_bounds__(256, 4) void main_kernel(const float* __restrict__ x,
                                                      const float* __restrict__ meang,
                                                      const _Float16* __restrict__ Ktg,
                                                      float* __restrict__ out) {
  __shared__ alignas(16) char smem[4 * SLICE_B];      // 33792 B
  int tid = threadIdx.x;
  int wave = tid >> 6, lane = tid & 63;
  int hf = lane >> 5, li = lane & 31;
  int c0 = 4 * li;
  int m0 = wave * 16;                    // wave-private 16 rows of the 64-row tile
  int l15 = lane & 15, lg = lane >> 4;
  char* vslice = smem + wave * SLICE_B;
  float* epi = (float*)(smem + wave * SLICE_B);       // aliases vslice (see above)

  int chunk = blockIdx.x;                // grid == NCHUNK: one chunk per block
  int row0 = chunk * TILE;
  int bb = chunk >> 4;                   // T/TILE = 16 chunks per batch
  const float* mb = meang + bb * D_CH;
  f32x4 mn = *(const f32x4*)(mb + c0);

  // ---- phase 1: load y,w; exp; store intensity; softmax; v -> LDS (f16 row-major) ----
  f32x4 yb[8], wb[8];
#pragma unroll
  for (int i = 0; i < 8; ++i) {
    size_t base = (size_t)(row0 + m0 + 2 * i + hf) * ROWLEN + c0;
    yb[i] = __builtin_nontemporal_load((const f32x4*)(x + base));
    wb[i] = __builtin_nontemporal_load((const f32x4*)(x + base + 128));
  }
#pragma unroll
  for (int i = 0; i < 8; ++i) {
    int lr = 2 * i + hf;
    int row = row0 + m0 + lr;
    f32x4 e;
    e[0] = __expf(wb[i][0]); e[1] = __expf(wb[i][1]);
    e[2] = __expf(wb[i][2]); e[3] = __expf(wb[i][3]);
    __builtin_nontemporal_store(e, (f32x4*)(out + (size_t)row * ROWLEN + 128 + c0));  // intensity
    float s = e[0] + e[1] + e[2] + e[3];                      // |w| small: no max-sub needed
    s += __shfl_xor(s, 1, 32);
    s += __shfl_xor(s, 2, 32);
    s += __shfl_xor(s, 4, 32);
    s += __shfl_xor(s, 8, 32);
    s += __shfl_xor(s, 16, 32);
    float rinv = 1.0f / s;
    f16x4 vh;
    vh[0] = (_Float16)(e[0] * rinv * (yb[i][0] - mn[0]));
    vh[1] = (_Float16)(e[1] * rinv * (yb[i][1] - mn[1]));
    vh[2] = (_Float16)(e[2] * rinv * (yb[i][2] - mn[2]));
    vh[3] = (_Float16)(e[3] * rinv * (yb[i][3] - mn[3]));
    *(f16x4*)(vslice + lr * VSTR_B + li * 8) = vh;
  }

  // ---- phase 2: A-frags from LDS, B-frags from global frag-order table (L2-hot 32KB) ----
  f16x8 a[4];
#pragma unroll
  for (int ks = 0; ks < 4; ++ks)
    a[ks] = *(const f16x8*)(vslice + l15 * VSTR_B + ks * 64 + lg * 16);
  f32x4 acc[8];
#pragma unroll
  for (int nt = 0; nt < 8; ++nt) {
    acc[nt] = (f32x4){0.f, 0.f, 0.f, 0.f};
#pragma unroll
    for (int ks = 0; ks < 4; ++ks) {
      f16x8 bf = *(const f16x8*)&Ktg[((nt * 4 + ks) * 64 + lane) * 8];
      acc[nt] = __builtin_amdgcn_mfma_f32_16x16x32_f16(a[ks], bf, acc[nt], 0, 0, 0);
    }
  }

  // ---- epilogue: C-layout -> LDS pane (2-way max banks), read back row-major f32x4 ----
  // (acc depends on all a[] ds_reads, so these ds_writes cannot overtake them)
#pragma unroll
  for (int nt = 0; nt < 8; ++nt)
#pragma unroll
    for (int r = 0; r < 4; ++r)
      epi[(lg * 4 + r) * EPI_W + nt * 16 + l15] = acc[nt][r];

#pragma unroll
  for (int i = 0; i < 8; ++i) {
    int lr = 2 * i + hf;
    size_t ob = (size_t)(row0 + m0 + lr) * ROWLEN;
    f32x4 sm4 = *(const f32x4*)&epi[lr * EPI_W + c0];
    sm4 += mn;
    f32x4 yo = __builtin_nontemporal_load((const f32x4*)(x + ob + 256 + c0));
    __builtin_nontemporal_store(sm4, (f32x4*)(out + ob + c0));                    // smooth
    f32x4 yt = yo - sm4;
    __builtin_nontemporal_store(yt, (f32x4*)(out + ob + 256 + c0));               // y_trans
  }
}

extern "C" void kernel_launch(void* const* d_in, const int* in_sizes, int n_in,
                              void* d_out, int out_size, void* d_ws, size_t ws_size,
                              hipStream_t stream) {
  const float* x = (const float*)d_in[0];
  const float* Kmat = (const float*)d_in[1];
  float* out = (float*)d_out;
  float* meang = (float*)d_ws;                          // 128*128 f32 = 64 KB
  _Float16* Ktg = (_Float16*)((char*)d_ws + 65536);     // 16384 f16 = 32 KB (frag order)
  prep_kernel<<<256, 1024, 0, stream>>>(x, Kmat, meang, Ktg);
  main_kernel<<<NCHUNK, 256, 0, stream>>>(x, meang, Ktg, out);
}

// Round 2
// 336.492 us; speedup vs baseline: 1.0408x; 1.0218x over previous
//
#include <hip/hip_runtime.h>
#include <cstdint>

#define D_CH 128
#define T_LEN 1024
#define ROWLEN 384
#define NROWS (128 * 1024)
#define TILE 64
#define NCHUNK (NROWS / TILE)   // 2048
#define VSTR_B 272              // vs row stride bytes (136 f16) — conflict-free b128 reads
#define EPI_W 132               // epi row stride words (pad 4) — 2-way max banks on scatter
#define SLICE_B 8448            // per-wave UNIFIED slice = max(16*VSTR_B=4352, 16*EPI_W*4=8448)

typedef __attribute__((ext_vector_type(8))) _Float16 f16x8;
typedef __attribute__((ext_vector_type(4))) _Float16 f16x4;
typedef __attribute__((ext_vector_type(4))) float f32x4;

// Kernel A: per-(b,d) partial means over T (S-way split across blocks for 2x CU
// parallelism) + kernel matrix -> f16 in MFMA-B fragment order.
// Each partial is pre-scaled by 1/1024; main sums the S partials.
// Loads stay NORMAL (not nt) so y warms L3 for main.
__global__ __launch_bounds__(1024) void prep_kernel(const float* __restrict__ x,
                                                    const float* __restrict__ Kmat,
                                                    float* __restrict__ meang,
                                                    _Float16* __restrict__ Ktg,
                                                    int S, int JITER) {
  int bid = blockIdx.x;            // 256*S blocks: (b, half-of-D, tq)
  int bh = bid / S;
  int tq = bid - bh * S;
  int b = bh >> 1, h = bh & 1;
  int tid = threadIdx.x;
  int li = tid & 15, tt = tid >> 4;      // 16 d-groups x 64 t-slices
  int d4 = h * 64 + 4 * li;
  f32x4 s = {0.f, 0.f, 0.f, 0.f};
  const float* xp = x + (size_t)b * T_LEN * ROWLEN + d4;
  int t0 = tq * (T_LEN / S) + tt;
#pragma unroll 4
  for (int j = 0; j < JITER; ++j) {
    int t = t0 + 64 * j;
    f32x4 v = *(const f32x4*)(xp + (size_t)t * ROWLEN);
    s += v;
  }
  __shared__ f32x4 red[64][17];          // 17408 B
  red[tt][li] = s;
  __syncthreads();
  for (int st = 32; st > 0; st >>= 1) {
    if (tt < st) red[tt][li] += red[tt + st][li];
    __syncthreads();
  }
  if (tt == 0) {
    f32x4 m = red[0][li] * (1.0f / 1024.0f);
    *(f32x4*)(meang + (size_t)(b * S + tq) * D_CH + d4) = m;
  }
  // fragment-order Kt: 64 f16 per (b,h) (16384 total, bijective); tq==0 blocks only
  if (tq == 0 && tid < 64) {
    int f = bh * 64 + tid;
    int j = f & 7;
    int lane = (f >> 3) & 63;
    int q = f >> 9;                 // 0..31 = nt*4 + ks
    int ks = q & 3, nt = q >> 2;
    int kk = ks * 32 + (lane >> 4) * 8 + j;
    int nn = nt * 16 + (lane & 15);
    Ktg[f] = (_Float16)Kmat[kk * D_CH + nn];
  }
}

// Kernel B: fused softmax + MFMA matmul + vectorized epilogue. ZERO barriers.
// Changes vs prev round:
//  - y_obs loads issued right after the v->LDS writes, BEFORE the A-frag ds_reads
//    and MFMA: the LDS-read + 32xMFMA + epi-staging stretch hides their ~900cy HBM
//    latency instead of exposing it as a dead-wait in the epilogue (VALUBusy was
//    1.4% — waves were pure memory-stall). Peak live regs ~105 < 128 cap.
//  - mn = sum of S pre-scaled partial means (S=2 when workspace allows).
__global__ __launch_bounds__(256, 4) void main_kernel(const float* __restrict__ x,
                                                      const float* __restrict__ meang,
                                                      const _Float16* __restrict__ Ktg,
                                                      float* __restrict__ out,
                                                      int S) {
  __shared__ alignas(16) char smem[4 * SLICE_B];      // 33792 B -> 4 blocks/CU
  int tid = threadIdx.x;
  int wave = tid >> 6, lane = tid & 63;
  int hf = lane >> 5, li = lane & 31;
  int c0 = 4 * li;
  int m0 = wave * 16;                    // wave-private 16 rows of the 64-row tile
  int l15 = lane & 15, lg = lane >> 4;
  char* vslice = smem + wave * SLICE_B;
  float* epi = (float*)(smem + wave * SLICE_B);       // aliases vslice (WAR-safe: in-order DS
                                                      // pipe + acc data-dep on a[] ds_reads)
  int chunk = blockIdx.x;                // grid == NCHUNK: one chunk per block
  int row0 = chunk * TILE;
  int bb = chunk >> 4;                   // T/TILE = 16 chunks per batch
  f32x4 mn = {0.f, 0.f, 0.f, 0.f};
  for (int s = 0; s < S; ++s)
    mn += *(const f32x4*)(meang + (size_t)(bb * S + s) * D_CH + c0);

  // ---- phase 1: load y,w; exp; store intensity; softmax; v -> LDS (f16 row-major) ----
  f32x4 yb[8], wb[8];
#pragma unroll
  for (int i = 0; i < 8; ++i) {
    size_t base = (size_t)(row0 + m0 + 2 * i + hf) * ROWLEN + c0;
    yb[i] = __builtin_nontemporal_load((const f32x4*)(x + base));
    wb[i] = __builtin_nontemporal_load((const f32x4*)(x + base + 128));
  }
#pragma unroll
  for (int i = 0; i < 8; ++i) {
    int lr = 2 * i + hf;
    int row = row0 + m0 + lr;
    f32x4 e;
    e[0] = __expf(wb[i][0]); e[1] = __expf(wb[i][1]);
    e[2] = __expf(wb[i][2]); e[3] = __expf(wb[i][3]);
    __builtin_nontemporal_store(e, (f32x4*)(out + (size_t)row * ROWLEN + 128 + c0));  // intensity
    float s = e[0] + e[1] + e[2] + e[3];                      // |w| small: no max-sub needed
    s += __shfl_xor(s, 1, 32);
    s += __shfl_xor(s, 2, 32);
    s += __shfl_xor(s, 4, 32);
    s += __shfl_xor(s, 8, 32);
    s += __shfl_xor(s, 16, 32);
    float rinv = 1.0f / s;
    f16x4 vh;
    vh[0] = (_Float16)(e[0] * rinv * (yb[i][0] - mn[0]));
    vh[1] = (_Float16)(e[1] * rinv * (yb[i][1] - mn[1]));
    vh[2] = (_Float16)(e[2] * rinv * (yb[i][2] - mn[2]));
    vh[3] = (_Float16)(e[3] * rinv * (yb[i][3] - mn[3]));
    *(f16x4*)(vslice + lr * VSTR_B + li * 8) = vh;
  }

  // ---- y_obs loads issued HERE: latency hides under LDS reads + MFMA + epi staging ----
  f32x4 yo[8];
#pragma unroll
  for (int i = 0; i < 8; ++i) {
    size_t base = (size_t)(row0 + m0 + 2 * i + hf) * ROWLEN + c0;
    yo[i] = __builtin_nontemporal_load((const f32x4*)(x + base + 256));
  }

  // ---- phase 2: A-frags from LDS, B-frags from global frag-order table (L2-hot 32KB) ----
  f16x8 a[4];
#pragma unroll
  for (int ks = 0; ks < 4; ++ks)
    a[ks] = *(const f16x8*)(vslice + l15 * VSTR_B + ks * 64 + lg * 16);
  f32x4 acc[8];
#pragma unroll
  for (int nt = 0; nt < 8; ++nt) {
    acc[nt] = (f32x4){0.f, 0.f, 0.f, 0.f};
#pragma unroll
    for (int ks = 0; ks < 4; ++ks) {
      f16x8 bf = *(const f16x8*)&Ktg[((nt * 4 + ks) * 64 + lane) * 8];
      acc[nt] = __builtin_amdgcn_mfma_f32_16x16x32_f16(a[ks], bf, acc[nt], 0, 0, 0);
    }
  }

  // ---- epilogue: C-layout -> LDS pane (2-way max banks), read back row-major f32x4 ----
  // (acc depends on all a[] ds_reads, so these ds_writes cannot overtake them)
#pragma unroll
  for (int nt = 0; nt < 8; ++nt)
#pragma unroll
    for (int r = 0; r < 4; ++r)
      epi[(lg * 4 + r) * EPI_W + nt * 16 + l15] = acc[nt][r];

#pragma unroll
  for (int i = 0; i < 8; ++i) {
    int lr = 2 * i + hf;
    size_t ob = (size_t)(row0 + m0 + lr) * ROWLEN;
    f32x4 sm4 = *(const f32x4*)&epi[lr * EPI_W + c0];
    sm4 += mn;
    __builtin_nontemporal_store(sm4, (f32x4*)(out + ob + c0));                    // smooth
    f32x4 yt = yo[i] - sm4;
    __builtin_nontemporal_store(yt, (f32x4*)(out + ob + 256 + c0));               // y_trans
  }
}

extern "C" void kernel_launch(void* const* d_in, const int* in_sizes, int n_in,
                              void* d_out, int out_size, void* d_ws, size_t ws_size,
                              hipStream_t stream) {
  const float* x = (const float*)d_in[0];
  const float* Kmat = (const float*)d_in[1];
  float* out = (float*)d_out;
  // S-way split prep needs S*64KB (partial means) + 32KB (Ktg); fall back if ws is tight
  int S = (ws_size >= (size_t)(2 * 65536 + 32768)) ? 2 : 1;
  float* meang = (float*)d_ws;                          // 128*S*128 f32
  _Float16* Ktg = (_Float16*)((char*)d_ws + (size_t)S * 65536);  // 16384 f16 (frag order)
  prep_kernel<<<256 * S, 1024, 0, stream>>>(x, Kmat, meang, Ktg, S, 16 / S);
  main_kernel<<<NCHUNK, 256, 0, stream>>>(x, meang, Ktg, out, S);
}